// Round 7
// baseline (788.817 us; speedup 1.0000x reference)
//
#include <hip/hip_runtime.h>
#include <math.h>

#define H 1024
#define W 1024
#define B 8
#define TOPK 4096
#define CAP 131072
#define NBIN 1024
#define NCH 32
#define GK 20480  // per-image gkeys: 4096 upper + 16384 cand cap
#define TILE_X 108
#define TILE_Y 44
#define GDX 10
#define GDY 24

typedef unsigned long long u64;
typedef unsigned int u32;

// bin monotone in key for v in [2^-7, 2); underflow -> bin 0
__device__ __forceinline__ int binOf(u64 key) {
    return ((key >> 58) == 0x0Full) ? (int)((key >> 48) & (NBIN - 1)) : 0;
}

// ================= Fused 3-round NMS + survivor compaction =================
// Region 128 wide x 64 tall per block; lane owns 2 adjacent columns (float2).
// 256 threads = 4 waves x 16 rows. Tile = [10,117]x[10,53] (108x44).

#define ROUND_A(VR0, VR1, USE_SUPP)                                               \
    _Pragma("unroll") for (int i = 0; i < 16; ++i) {                              \
        int r = rbase + i;                                                        \
        if (r < (VR0) || r > (VR1)) continue;                                     \
        float x = svx[i], y = svy[i];                                             \
        if (USE_SUPP) {                                                           \
            if ((spE[r] >> lane) & 1ull) x = (x == -INFINITY) ? x : 0.0f;         \
            if ((spO[r] >> lane) & 1ull) y = (y == -INFINITY) ? y : 0.0f;         \
        }                                                                         \
        float ux = __shfl_up(x, 1), uy = __shfl_up(y, 1);                         \
        float dxx = __shfl_down(x, 1), dyy = __shfl_down(y, 1);                   \
        float m01 = fmaxf(x, y);                                                  \
        float h0 = fmaxf(fmaxf(ux, uy), fmaxf(m01, dxx));                         \
        float h1 = fmaxf(fmaxf(uy, m01), fmaxf(dxx, dyy));                        \
        h0r[i] = h0;                                                              \
        h1r[i] = h1;                                                              \
        if (i == 0 || i == 1 || i == 14 || i == 15) {                             \
            int k = (i < 2) ? i : i - 12;                                         \
            *(float2*)&hb[w * 4 + k][2 * lane] = make_float2(h0, h1);             \
        }                                                                         \
    }

#define ROUND_B(VV0, VV1, CMIN, CMAX, USE_SUPP, OUTE, OUTO, INE, INO, FIRST)      \
    _Pragma("unroll") for (int i = 0; i < 16; ++i) {                              \
        int r = rbase + i;                                                        \
        if (r < (VV0) || r > (VV1)) continue;                                     \
        float v0x, v0y, v1x, v1y, v3x, v3y, v4x, v4y;                             \
        if (i >= 2) { v0x = h0r[i - 2]; v0y = h1r[i - 2]; }                       \
        else { int k = (i == 0) ? 2 : 3;                                          \
               float2 t = *(const float2*)&hb[(w - 1) * 4 + k][2 * lane];         \
               v0x = t.x; v0y = t.y; }                                            \
        if (i >= 1) { v1x = h0r[i - 1]; v1y = h1r[i - 1]; }                       \
        else { float2 t = *(const float2*)&hb[(w - 1) * 4 + 3][2 * lane];         \
               v1x = t.x; v1y = t.y; }                                            \
        if (i <= 14) { v3x = h0r[i + 1]; v3y = h1r[i + 1]; }                      \
        else { float2 t = *(const float2*)&hb[(w + 1) * 4 + 0][2 * lane];         \
               v3x = t.x; v3y = t.y; }                                            \
        if (i <= 13) { v4x = h0r[i + 2]; v4y = h1r[i + 2]; }                      \
        else { int k = (i == 14) ? 0 : 1;                                         \
               float2 t = *(const float2*)&hb[(w + 1) * 4 + k][2 * lane];         \
               v4x = t.x; v4y = t.y; }                                            \
        float vm0 = fmaxf(fmaxf(fmaxf(v0x, v1x), fmaxf(v3x, v4x)), h0r[i]);       \
        float vm1 = fmaxf(fmaxf(fmaxf(v0y, v1y), fmaxf(v3y, v4y)), h1r[i]);       \
        float x = svx[i], y = svy[i];                                             \
        bool sb0 = false, sb1 = false;                                            \
        if (USE_SUPP) {                                                           \
            sb0 = (spE[r] >> lane) & 1ull;                                        \
            sb1 = (spO[r] >> lane) & 1ull;                                        \
            if (sb0) x = (x == -INFINITY) ? x : 0.0f;                             \
            if (sb1) y = (y == -INFINITY) ? y : 0.0f;                             \
        }                                                                         \
        int c0 = 2 * lane;                                                        \
        bool bit0 = (x == vm0) && !sb0 && (svx[i] != -INFINITY) &&                \
                    c0 >= (CMIN) && c0 <= (CMAX);                                 \
        bool bit1 = (y == vm1) && !sb1 && (svy[i] != -INFINITY) &&                \
                    (c0 + 1) >= (CMIN) && (c0 + 1) <= (CMAX);                     \
        u64 bE = __ballot(bit0), bO = __ballot(bit1);                             \
        if (lane == 0) {                                                          \
            OUTE[r] = ((FIRST) ? 0ull : INE[r]) | bE;                             \
            OUTO[r] = ((FIRST) ? 0ull : INO[r]) | bO;                             \
        }                                                                         \
    }

#define DILATE(R0, R1, INE, INO)                                                  \
    if (tid >= (R0) && tid <= (R1)) {                                             \
        int rr = tid;                                                             \
        u64 e = INE[rr - 2] | INE[rr - 1] | INE[rr] | INE[rr + 1] | INE[rr + 2];  \
        u64 o = INO[rr - 2] | INO[rr - 1] | INO[rr] | INO[rr + 1] | INO[rr + 2];  \
        spE[rr] = e | (e << 1) | (e >> 1) | o | (o << 1);                         \
        spO[rr] = o | (o << 1) | (o >> 1) | e | (e >> 1);                         \
    }

__global__ __launch_bounds__(256) void k_nms(const float* __restrict__ scores,
                                             u64* __restrict__ surv,
                                             u32* __restrict__ cnt) {
    __shared__ float hb[16][128];
    __shared__ u64 maE[64], maO[64], mbE[64], mbO[64], spE[64], spO[64];
    __shared__ u64 skeys[640];
    __shared__ u32 lcnt, gbase;
    const int b = blockIdx.z;
    const int gx0 = blockIdx.x * TILE_X - 10;
    const int gy0 = blockIdx.y * TILE_Y - 10;
    const float* img = scores + (size_t)b * H * W;
    const int tid = (int)threadIdx.x, lane = tid & 63, w = tid >> 6, rbase = w * 16;
    const int gx = gx0 + 2 * lane;
    if (tid == 0) lcnt = 0;

    float svx[16], svy[16], h0r[16], h1r[16];
#pragma unroll
    for (int i = 0; i < 16; ++i) {
        int gy = gy0 + rbase + i;
        float x = -INFINITY, y = -INFINITY;
        if (gy >= 0 && gy < H) {
            const float* row = img + (size_t)gy * W;
            if (gx >= 0 && gx + 1 < W) {
                float2 t = *(const float2*)(row + gx);
                x = t.x; y = t.y;
            } else if (gx >= 0 && gx < W) {
                x = row[gx];
            }
        }
        svx[i] = x; svy[i] = y;
    }

    ROUND_A(0, 63, false)
    __syncthreads();
    ROUND_B(2, 61, 2, 125, false, maE, maO, maE, maO, 1)
    __syncthreads();
    DILATE(4, 59, maE, maO)
    __syncthreads();
    ROUND_A(4, 59, true)
    __syncthreads();
    ROUND_B(6, 57, 6, 121, true, mbE, mbO, maE, maO, 0)
    __syncthreads();
    DILATE(8, 55, mbE, mbO)
    __syncthreads();
    ROUND_A(8, 55, true)
    __syncthreads();
    ROUND_B(10, 53, 10, 117, true, maE, maO, mbE, mbO, 0)
    __syncthreads();

#pragma unroll
    for (int i = 0; i < 16; ++i) {
        int r = rbase + i;
        if (r < 10 || r > 53) continue;
        int gy = gy0 + r;
        u64 me = maE[r], mo = maO[r];
        int c0 = 2 * lane;
        if (c0 >= 10 && c0 <= 117 && ((me >> lane) & 1ull) && svx[i] > 0.0f &&
            gx >= 2 && gx < W - 2 && gy >= 2 && gy < H - 2) {
            u32 pos = atomicAdd(&lcnt, 1u);
            if (pos < 640u) {
                u32 p = (u32)(gy * W + gx);
                skeys[pos] = ((u64)__float_as_uint(svx[i]) << 32) | (u64)(~p);
            }
        }
        if (c0 + 1 >= 10 && c0 + 1 <= 117 && ((mo >> lane) & 1ull) && svy[i] > 0.0f &&
            gx + 1 >= 2 && gx + 1 < W - 2 && gy >= 2 && gy < H - 2) {
            u32 pos = atomicAdd(&lcnt, 1u);
            if (pos < 640u) {
                u32 p = (u32)(gy * W + gx + 1);
                skeys[pos] = ((u64)__float_as_uint(svy[i]) << 32) | (u64)(~p);
            }
        }
    }
    __syncthreads();
    u32 nk = lcnt < 640u ? lcnt : 640u;
    if (tid == 0) gbase = nk ? atomicAdd(&cnt[b], nk) : 0u;
    __syncthreads();
    for (u32 i = tid; i < nk; i += 256)
        surv[(size_t)b * CAP + gbase + i] = skeys[i];
}

// ===== per-chunk private histograms (no global atomics) =====
__global__ __launch_bounds__(256) void k_hist(const u64* __restrict__ surv,
                                              const u32* __restrict__ cnt,
                                              u32* __restrict__ M) {
    __shared__ u32 h[NBIN];
    int img = blockIdx.x / NCH, c = blockIdx.x % NCH;
    int tid = (int)threadIdx.x;
    for (int i = tid; i < NBIN; i += 256) h[i] = 0;
    __syncthreads();
    u32 n = cnt[img];
    if (n > CAP) n = CAP;
    u32 chunk = (n + NCH - 1) / NCH;
    u32 lo = c * chunk, hi = min(n, lo + chunk);
    const u64* sv = surv + (size_t)img * CAP;
    for (u32 i = lo + tid; i < hi; i += 256) atomicAdd(&h[binOf(sv[i])], 1u);
    __syncthreads();
    u32* dst = M + ((size_t)img * NCH + c) * NBIN;
    for (int i = tid; i < NBIN; i += 256) dst[i] = h[i];
}

// ===== scan: T + r, per-(chunk,bin) exclusive offsets, zero upper gkeys =====
__global__ __launch_bounds__(1024) void k_scan(const u32* __restrict__ M,
                                               u32* __restrict__ offo,
                                               u32* __restrict__ basetot,
                                               int* __restrict__ tinfo,
                                               u64* __restrict__ gkeys) {
    __shared__ u32 psum[NBIN];
    __shared__ int sh_T;
    __shared__ u32 sh_r, sh_m;
    int img = blockIdx.x, tid = (int)threadIdx.x;
    u32 m[NCH];
    u32 tot = 0;
    const u32* Mi = M + (size_t)img * NCH * NBIN;
#pragma unroll
    for (int c = 0; c < NCH; ++c) { m[c] = Mi[c * NBIN + tid]; tot += m[c]; }
    psum[tid] = tot;
    __syncthreads();
    for (int off = 1; off < NBIN; off <<= 1) {
        u32 v = (tid + off < NBIN) ? psum[tid + off] : 0u;
        __syncthreads();
        psum[tid] += v;
        __syncthreads();
    }
    u32 incl = psum[tid];          // sum over bins >= tid
    u32 excl = incl - tot;         // sum over bins > tid
    u32 ntot = psum[0];
    if (ntot > TOPK) {
        if (excl < TOPK && TOPK <= incl) { sh_T = tid; sh_r = TOPK - excl; sh_m = tot; }
    } else if (tid == 0) { sh_T = -1; sh_r = 0; sh_m = 0; }
    __syncthreads();
    int T = sh_T;
    u32 run;
    if (tid > T) run = excl;          // upper-segment base (bins desc)
    else if (tid == T) run = TOPK;    // candidate region base
    else run = 0;                      // unused (skipped in scatter)
    u32* off_img = offo + (size_t)img * NCH * NBIN;
#pragma unroll
    for (int c = 0; c < NCH; ++c) { off_img[c * NBIN + tid] = run; run += m[c]; }
    basetot[(size_t)img * NBIN + tid] = (tid > T) ? ((excl << 16) | tot) : 0u;
    u64* gk = gkeys + (size_t)img * GK;
    for (int i = tid; i < TOPK; i += 1024) gk[i] = 0ull;
    if (tid == 0) {
        tinfo[3 * img] = T;
        tinfo[3 * img + 1] = (int)sh_r;
        tinfo[3 * img + 2] = (int)sh_m;
    }
}

// ===== scatter survivors into exact segment slots (LDS offsets only) =====
__global__ __launch_bounds__(256) void k_scatter(const u64* __restrict__ surv,
                                                 const u32* __restrict__ cnt,
                                                 const int* __restrict__ tinfo,
                                                 const u32* __restrict__ offo,
                                                 u64* __restrict__ gkeys) {
    __shared__ u32 loff[NBIN];
    int img = blockIdx.x / NCH, c = blockIdx.x % NCH;
    int tid = (int)threadIdx.x;
    const u32* src = offo + ((size_t)img * NCH + c) * NBIN;
    for (int i = tid; i < NBIN; i += 256) loff[i] = src[i];
    __syncthreads();
    u32 n = cnt[img];
    if (n > CAP) n = CAP;
    u32 chunk = (n + NCH - 1) / NCH;
    u32 lo = c * chunk, hi = min(n, lo + chunk);
    int T = tinfo[3 * img];
    const u64* sv = surv + (size_t)img * CAP;
    u64* gk = gkeys + (size_t)img * GK;
    for (u32 i = lo + tid; i < hi; i += 256) {
        u64 kk = sv[i];
        int bb = binOf(kk);
        if (bb < T) continue;
        u32 slot = atomicAdd(&loff[bb], 1u);
        if (slot < GK) gk[slot] = kk;
    }
}

// ===== finalize: exact candidate ranks + within-segment ranks -> sorted =====
__global__ __launch_bounds__(1024) void k_fin(const int* __restrict__ tinfo,
                                              const u32* __restrict__ basetot,
                                              const u64* __restrict__ gkeys,
                                              u64* __restrict__ sorted) {
    __shared__ u64 up[TOPK];
    __shared__ u64 cnd[4096];
    __shared__ u32 bt[NBIN];
    int img = blockIdx.x, tid = (int)threadIdx.x;
    int T = tinfo[3 * img];
    u32 r = (u32)tinfo[3 * img + 1];
    u32 m = (u32)tinfo[3 * img + 2];
    if (m > 4096u) m = 4096u;
    const u64* gk = gkeys + (size_t)img * GK;
    for (int i = tid; i < TOPK; i += 1024) up[i] = gk[i];
    for (u32 i = tid; i < m; i += 1024) cnd[i] = gk[TOPK + i];
    for (int i = tid; i < NBIN; i += 1024) bt[i] = basetot[(size_t)img * NBIN + i];
    __syncthreads();
    u64* dst = sorted + (size_t)img * TOPK;
    // threshold-bin candidates -> slots [TOPK-r, TOPK)
    for (u32 i = tid; i < m; i += 1024) {
        u64 ki = cnd[i];
        u32 g = 0;
        for (u32 j = 0; j < m; ++j) g += (cnd[j] > ki) ? 1u : 0u;
        if (g < r) dst[TOPK - r + g] = ki;
    }
    // upper keys: exact rank within their bin segment
    u32 upper = TOPK - r;
    for (u32 s = tid; s < upper; s += 1024) {
        u64 kk = up[s];
        if (kk == 0ull) { dst[s] = 0ull; continue; }
        int bb = binOf(kk);
        u32 v = bt[bb];
        u32 base = v >> 16, c = v & 0xFFFFu;
        u32 g = 0;
        for (u32 j = 0; j < c; ++j) g += (up[base + j] > kk) ? 1u : 0u;
        dst[base + g] = kk;
    }
}

// -------- Per-keypoint soft-argmax / dispersity / bilinear sample --------
__global__ __launch_bounds__(64) void k_out(const float* __restrict__ scores,
                                            const u64* __restrict__ sorted,
                                            float* __restrict__ out) {
    int gid = blockIdx.x * 64 + threadIdx.x;
    int b = gid / TOPK;
    int kp = gid & (TOPK - 1);
    const float* img = scores + (size_t)b * H * W;
    u64 key = sorted[(size_t)b * TOPK + kp];
    u32 idx = ~(u32)(key & 0xFFFFFFFFull);
    int ky = (int)(idx >> 10), kx = (int)(idx & 1023);
    ky = min(max(ky, 2), H - 3);
    kx = min(max(kx, 2), W - 3);
    float patch[25];
    float mx = -INFINITY;
#pragma unroll
    for (int dy = 0; dy < 5; ++dy)
#pragma unroll
        for (int dx = 0; dx < 5; ++dx) {
            float v = img[(ky + dy - 2) * W + (kx + dx - 2)];
            patch[dy * 5 + dx] = v;
            mx = fmaxf(mx, v);
        }
    float e[25];
    float ssum = 0.f, ex = 0.f, ey = 0.f;
#pragma unroll
    for (int p = 0; p < 25; ++p) {
        float t = expf((patch[p] - mx) / 0.1f);
        e[p] = t;
        ssum += t;
        ex += t * (float)((p % 5) - 2);
        ey += t * (float)((p / 5) - 2);
    }
    float xr = ex / ssum, yr = ey / ssum;
    float disp = 0.f;
#pragma unroll
    for (int p = 0; p < 25; ++p) {
        float ddx = ((float)((p % 5) - 2) - xr) * 0.5f;
        float ddy = ((float)((p / 5) - 2) - yr) * 0.5f;
        disp += e[p] * (ddx * ddx + ddy * ddy);
    }
    disp /= ssum;
    float kpx = ((float)kx + xr) / 1023.0f * 2.0f - 1.0f;
    float kpy = ((float)ky + yr) / 1023.0f * 2.0f - 1.0f;
    float px = (kpx + 1.0f) * 0.5f * 1023.0f;
    float py = (kpy + 1.0f) * 0.5f * 1023.0f;
    float fx = floorf(px), fy = floorf(py);
    float wx = px - fx, wy = py - fy;
    int x0 = (int)fminf(fmaxf(fx, 0.f), 1023.f);
    int x1 = (int)fminf(fmaxf(fx + 1.f, 0.f), 1023.f);
    int y0 = (int)fminf(fmaxf(fy, 0.f), 1023.f);
    int y1 = (int)fminf(fmaxf(fy + 1.f, 0.f), 1023.f);
    float v00 = img[y0 * W + x0], v01 = img[y0 * W + x1];
    float v10 = img[y1 * W + x0], v11 = img[y1 * W + x1];
    float sc = v00 * (1.f - wx) * (1.f - wy) + v01 * wx * (1.f - wy) +
               v10 * (1.f - wx) * wy + v11 * wx * wy;
    size_t kb = (size_t)b * TOPK + kp;
    out[kb * 2 + 0] = kpx;
    out[kb * 2 + 1] = kpy;
    out[(size_t)B * TOPK * 2 + kb] = disp;
    out[(size_t)B * TOPK * 3 + kb] = sc;
}

extern "C" void kernel_launch(void* const* d_in, const int* in_sizes, int n_in,
                              void* d_out, int out_size, void* d_ws, size_t ws_size,
                              hipStream_t stream) {
    const float* scores = (const float*)d_in[0];
    float* out = (float*)d_out;
    char* ws = (char*)d_ws;
    u64* surv = (u64*)ws;                                   // 8 MB
    u32* M = (u32*)(ws + 8388608);                          // 1 MB
    u32* offo = (u32*)(ws + 9437184);                       // 1 MB
    u32* basetot = (u32*)(ws + 10485760);                   // 32 KB
    u64* gkeys = (u64*)(ws + 10518528);                     // 1.25 MB
    u64* sorted = (u64*)(ws + 11829248);                    // 256 KB
    u32* cnt = (u32*)(ws + 12091392);                       // 32 B
    int* tinfo = (int*)(ws + 12091456);                     // 96 B

    hipMemsetAsync(cnt, 0, B * sizeof(u32), stream);

    k_nms<<<dim3(GDX, GDY, B), 256, 0, stream>>>(scores, surv, cnt);
    k_hist<<<B * NCH, 256, 0, stream>>>(surv, cnt, M);
    k_scan<<<B, 1024, 0, stream>>>(M, offo, basetot, tinfo, gkeys);
    k_scatter<<<B * NCH, 256, 0, stream>>>(surv, cnt, tinfo, offo, gkeys);
    k_fin<<<B, 1024, 0, stream>>>(tinfo, basetot, gkeys, sorted);
    k_out<<<(B * TOPK) / 64, 64, 0, stream>>>(scores, sorted, out);
}

// Round 8
// 157.442 us; speedup vs baseline: 5.0102x; 5.0102x over previous
//
#include <hip/hip_runtime.h>
#include <math.h>

#define H 1024
#define W 1024
#define B 8
#define TOPK 4096
#define CAP 131072
#define NBT 16384
#define NCH 8
#define GK 20480  // per-image gkeys: 4096 upper + 16384 cand cap
#define TILE_X 108
#define TILE_Y 44
#define GDX 10
#define GDY 24

typedef unsigned long long u64;
typedef unsigned int u32;

// Monotone bin index, fine-grained where survivor values cluster (v in [0.5,1)).
// exp==0x7E: bins 64..16383 via mantissa[22:9] (width ~3e-5 -> ~32 keys/bin).
// Lower exponents -> coarse monotone bins (all far below the top-4096 threshold).
__device__ __forceinline__ int binOf(u64 key) {
    u32 fb = (u32)(key >> 32);
    u32 ex = fb >> 23;  // sign always 0 (v > 0)
    if (ex >= 0x7Fu) return NBT - 1;
    if (ex == 0x7Eu) {
        u32 m14 = (fb >> 9) & 0x3FFFu;
        return (m14 < 64u) ? 64 : (int)m14;
    }
    if (ex >= 0x6Eu) return (int)(ex - 0x6Eu + 47u);  // 47..62
    return 1;
}

// ================= Fused 3-round NMS + survivor compaction =================
// Region 128 wide x 64 tall per block; lane owns 2 adjacent columns (float2).
// 256 threads = 4 waves x 16 rows. Tile = [10,117]x[10,53] (108x44).

#define ROUND_A(VR0, VR1, USE_SUPP)                                               \
    _Pragma("unroll") for (int i = 0; i < 16; ++i) {                              \
        int r = rbase + i;                                                        \
        if (r < (VR0) || r > (VR1)) continue;                                     \
        float x = svx[i], y = svy[i];                                             \
        if (USE_SUPP) {                                                           \
            if ((spE[r] >> lane) & 1ull) x = (x == -INFINITY) ? x : 0.0f;         \
            if ((spO[r] >> lane) & 1ull) y = (y == -INFINITY) ? y : 0.0f;         \
        }                                                                         \
        float ux = __shfl_up(x, 1), uy = __shfl_up(y, 1);                         \
        float dxx = __shfl_down(x, 1), dyy = __shfl_down(y, 1);                   \
        float m01 = fmaxf(x, y);                                                  \
        float h0 = fmaxf(fmaxf(ux, uy), fmaxf(m01, dxx));                         \
        float h1 = fmaxf(fmaxf(uy, m01), fmaxf(dxx, dyy));                        \
        h0r[i] = h0;                                                              \
        h1r[i] = h1;                                                              \
        if (i == 0 || i == 1 || i == 14 || i == 15) {                             \
            int k = (i < 2) ? i : i - 12;                                         \
            *(float2*)&hb[w * 4 + k][2 * lane] = make_float2(h0, h1);             \
        }                                                                         \
    }

#define ROUND_B(VV0, VV1, CMIN, CMAX, USE_SUPP, OUTE, OUTO, INE, INO, FIRST)      \
    _Pragma("unroll") for (int i = 0; i < 16; ++i) {                              \
        int r = rbase + i;                                                        \
        if (r < (VV0) || r > (VV1)) continue;                                     \
        float v0x, v0y, v1x, v1y, v3x, v3y, v4x, v4y;                             \
        if (i >= 2) { v0x = h0r[i - 2]; v0y = h1r[i - 2]; }                       \
        else { int k = (i == 0) ? 2 : 3;                                          \
               float2 t = *(const float2*)&hb[(w - 1) * 4 + k][2 * lane];         \
               v0x = t.x; v0y = t.y; }                                            \
        if (i >= 1) { v1x = h0r[i - 1]; v1y = h1r[i - 1]; }                       \
        else { float2 t = *(const float2*)&hb[(w - 1) * 4 + 3][2 * lane];         \
               v1x = t.x; v1y = t.y; }                                            \
        if (i <= 14) { v3x = h0r[i + 1]; v3y = h1r[i + 1]; }                      \
        else { float2 t = *(const float2*)&hb[(w + 1) * 4 + 0][2 * lane];         \
               v3x = t.x; v3y = t.y; }                                            \
        if (i <= 13) { v4x = h0r[i + 2]; v4y = h1r[i + 2]; }                      \
        else { int k = (i == 14) ? 0 : 1;                                         \
               float2 t = *(const float2*)&hb[(w + 1) * 4 + k][2 * lane];         \
               v4x = t.x; v4y = t.y; }                                            \
        float vm0 = fmaxf(fmaxf(fmaxf(v0x, v1x), fmaxf(v3x, v4x)), h0r[i]);       \
        float vm1 = fmaxf(fmaxf(fmaxf(v0y, v1y), fmaxf(v3y, v4y)), h1r[i]);       \
        float x = svx[i], y = svy[i];                                             \
        bool sb0 = false, sb1 = false;                                            \
        if (USE_SUPP) {                                                           \
            sb0 = (spE[r] >> lane) & 1ull;                                        \
            sb1 = (spO[r] >> lane) & 1ull;                                        \
            if (sb0) x = (x == -INFINITY) ? x : 0.0f;                             \
            if (sb1) y = (y == -INFINITY) ? y : 0.0f;                             \
        }                                                                         \
        int c0 = 2 * lane;                                                        \
        bool bit0 = (x == vm0) && !sb0 && (svx[i] != -INFINITY) &&                \
                    c0 >= (CMIN) && c0 <= (CMAX);                                 \
        bool bit1 = (y == vm1) && !sb1 && (svy[i] != -INFINITY) &&                \
                    (c0 + 1) >= (CMIN) && (c0 + 1) <= (CMAX);                     \
        u64 bE = __ballot(bit0), bO = __ballot(bit1);                             \
        if (lane == 0) {                                                          \
            OUTE[r] = ((FIRST) ? 0ull : INE[r]) | bE;                             \
            OUTO[r] = ((FIRST) ? 0ull : INO[r]) | bO;                             \
        }                                                                         \
    }

#define DILATE(R0, R1, INE, INO)                                                  \
    if (tid >= (R0) && tid <= (R1)) {                                             \
        int rr = tid;                                                             \
        u64 e = INE[rr - 2] | INE[rr - 1] | INE[rr] | INE[rr + 1] | INE[rr + 2];  \
        u64 o = INO[rr - 2] | INO[rr - 1] | INO[rr] | INO[rr + 1] | INO[rr + 2];  \
        spE[rr] = e | (e << 1) | (e >> 1) | o | (o << 1);                         \
        spO[rr] = o | (o << 1) | (o >> 1) | e | (e >> 1);                         \
    }

__global__ __launch_bounds__(256) void k_nms(const float* __restrict__ scores,
                                             u64* __restrict__ surv,
                                             u32* __restrict__ cnt) {
    __shared__ float hb[16][128];
    __shared__ u64 maE[64], maO[64], mbE[64], mbO[64], spE[64], spO[64];
    __shared__ u64 skeys[640];
    __shared__ u32 lcnt, gbase;
    const int b = blockIdx.z;
    const int gx0 = blockIdx.x * TILE_X - 10;
    const int gy0 = blockIdx.y * TILE_Y - 10;
    const float* img = scores + (size_t)b * H * W;
    const int tid = (int)threadIdx.x, lane = tid & 63, w = tid >> 6, rbase = w * 16;
    const int gx = gx0 + 2 * lane;
    if (tid == 0) lcnt = 0;

    float svx[16], svy[16], h0r[16], h1r[16];
#pragma unroll
    for (int i = 0; i < 16; ++i) {
        int gy = gy0 + rbase + i;
        float x = -INFINITY, y = -INFINITY;
        if (gy >= 0 && gy < H) {
            const float* row = img + (size_t)gy * W;
            if (gx >= 0 && gx + 1 < W) {
                float2 t = *(const float2*)(row + gx);
                x = t.x; y = t.y;
            } else if (gx >= 0 && gx < W) {
                x = row[gx];
            }
        }
        svx[i] = x; svy[i] = y;
    }

    ROUND_A(0, 63, false)
    __syncthreads();
    ROUND_B(2, 61, 2, 125, false, maE, maO, maE, maO, 1)
    __syncthreads();
    DILATE(4, 59, maE, maO)
    __syncthreads();
    ROUND_A(4, 59, true)
    __syncthreads();
    ROUND_B(6, 57, 6, 121, true, mbE, mbO, maE, maO, 0)
    __syncthreads();
    DILATE(8, 55, mbE, mbO)
    __syncthreads();
    ROUND_A(8, 55, true)
    __syncthreads();
    ROUND_B(10, 53, 10, 117, true, maE, maO, mbE, mbO, 0)
    __syncthreads();

#pragma unroll
    for (int i = 0; i < 16; ++i) {
        int r = rbase + i;
        if (r < 10 || r > 53) continue;
        int gy = gy0 + r;
        u64 me = maE[r], mo = maO[r];
        int c0 = 2 * lane;
        if (c0 >= 10 && c0 <= 117 && ((me >> lane) & 1ull) && svx[i] > 0.0f &&
            gx >= 2 && gx < W - 2 && gy >= 2 && gy < H - 2) {
            u32 pos = atomicAdd(&lcnt, 1u);
            if (pos < 640u) {
                u32 p = (u32)(gy * W + gx);
                skeys[pos] = ((u64)__float_as_uint(svx[i]) << 32) | (u64)(~p);
            }
        }
        if (c0 + 1 >= 10 && c0 + 1 <= 117 && ((mo >> lane) & 1ull) && svy[i] > 0.0f &&
            gx + 1 >= 2 && gx + 1 < W - 2 && gy >= 2 && gy < H - 2) {
            u32 pos = atomicAdd(&lcnt, 1u);
            if (pos < 640u) {
                u32 p = (u32)(gy * W + gx + 1);
                skeys[pos] = ((u64)__float_as_uint(svy[i]) << 32) | (u64)(~p);
            }
        }
    }
    __syncthreads();
    u32 nk = lcnt < 640u ? lcnt : 640u;
    if (tid == 0) gbase = nk ? atomicAdd(&cnt[b], nk) : 0u;
    __syncthreads();
    for (u32 i = tid; i < nk; i += 256)
        surv[(size_t)b * CAP + gbase + i] = skeys[i];
}

// ===== per-chunk private histograms (no global atomics) =====
__global__ __launch_bounds__(256) void k_hist(const u64* __restrict__ surv,
                                              const u32* __restrict__ cnt,
                                              u32* __restrict__ M) {
    __shared__ u32 h[NBT];
    int img = blockIdx.x / NCH, c = blockIdx.x % NCH;
    int tid = (int)threadIdx.x;
    for (int i = tid; i < NBT; i += 256) h[i] = 0;
    __syncthreads();
    u32 n = cnt[img];
    if (n > CAP) n = CAP;
    u32 chunk = (n + NCH - 1) / NCH;
    u32 lo = c * chunk, hi = min(n, lo + chunk);
    const u64* sv = surv + (size_t)img * CAP;
    for (u32 i = lo + tid; i < hi; i += 256) atomicAdd(&h[binOf(sv[i])], 1u);
    __syncthreads();
    u32* dst = M + ((size_t)img * NCH + c) * NBT;
    for (int i = tid; i < NBT; i += 256) dst[i] = h[i];
}

// ===== scan: T + r, per-(bin,chunk) exclusive offsets for bins >= T =====
__global__ __launch_bounds__(1024) void k_scan(const u32* __restrict__ M,
                                               u32* __restrict__ offo,
                                               u32* __restrict__ basetot,
                                               int* __restrict__ tinfo,
                                               u64* __restrict__ gkeys) {
    __shared__ u32 psum[1024];
    __shared__ int sh_T;
    __shared__ u32 sh_r, sh_m;
    int img = blockIdx.x, tid = (int)threadIdx.x;
    const u32* Mi = M + (size_t)img * NCH * NBT;
    int hi = NBT - 1 - tid * 16;
    u32 cnts[16];
    u32 tot = 0;
#pragma unroll
    for (int j = 0; j < 16; ++j) {
        u32 s = 0;
        for (int c = 0; c < NCH; ++c) s += Mi[c * NBT + (hi - j)];
        cnts[j] = s;
        tot += s;
    }
    psum[tid] = tot;
    __syncthreads();
    for (int off = 1; off < 1024; off <<= 1) {
        u32 v = (tid >= off) ? psum[tid - off] : 0u;
        __syncthreads();
        psum[tid] += v;
        __syncthreads();
    }
    u32 incl = psum[tid], excl = incl - tot, ntot = psum[1023];
    if (ntot > TOPK) {
        if (excl < TOPK && TOPK <= incl) {
            u32 cum = excl;
#pragma unroll
            for (int j = 0; j < 16; ++j) {
                if (cum + cnts[j] >= TOPK) {
                    sh_T = hi - j;
                    sh_r = TOPK - cum;
                    sh_m = cnts[j];
                    break;
                }
                cum += cnts[j];
            }
        }
    } else if (tid == 0) { sh_T = -1; sh_r = 0; sh_m = 0; }
    __syncthreads();
    int T = sh_T;
    u32* offi = offo + (size_t)img * NCH * NBT;
    u32* bti = basetot + (size_t)img * NBT;
    u32 cum = excl;
#pragma unroll
    for (int j = 0; j < 16; ++j) {
        int bin = hi - j;
        u32 c0 = cnts[j];
        if (bin > T) {
            u32 run = cum;
            for (int c = 0; c < NCH; ++c) {
                offi[(size_t)bin * NCH + c] = run;
                run += Mi[c * NBT + bin];
            }
            bti[bin] = (cum << 16) | c0;
        } else if (bin == T) {
            u32 run = TOPK;  // candidate region base
            for (int c = 0; c < NCH; ++c) {
                offi[(size_t)bin * NCH + c] = run;
                run += Mi[c * NBT + bin];
            }
        }
        cum += c0;
    }
    u64* gk = gkeys + (size_t)img * GK;
    for (int i = tid; i < TOPK; i += 1024) gk[i] = 0ull;
    if (tid == 0) {
        tinfo[3 * img] = T;
        tinfo[3 * img + 1] = (int)sh_r;
        tinfo[3 * img + 2] = (int)sh_m;
    }
}

// ===== scatter survivors into exact segment slots (LDS offsets only) =====
__global__ __launch_bounds__(256) void k_scatter(const u64* __restrict__ surv,
                                                 const u32* __restrict__ cnt,
                                                 const int* __restrict__ tinfo,
                                                 const u32* __restrict__ offo,
                                                 u64* __restrict__ gkeys) {
    __shared__ u32 loff[NBT];
    int img = blockIdx.x / NCH, c = blockIdx.x % NCH;
    int tid = (int)threadIdx.x;
    const u32* src = offo + (size_t)img * NCH * NBT;
    for (int i = tid; i < NBT; i += 256) loff[i] = src[(size_t)i * NCH + c];
    __syncthreads();
    u32 n = cnt[img];
    if (n > CAP) n = CAP;
    u32 chunk = (n + NCH - 1) / NCH;
    u32 lo = c * chunk, hiX = min(n, lo + chunk);
    int T = tinfo[3 * img];
    const u64* sv = surv + (size_t)img * CAP;
    u64* gk = gkeys + (size_t)img * GK;
    for (u32 i = lo + tid; i < hiX; i += 256) {
        u64 kk = sv[i];
        int bb = binOf(kk);
        if (bb < T) continue;
        u32 slot = atomicAdd(&loff[bb], 1u);
        if (slot < GK) gk[slot] = kk;
    }
}

// ===== finalize: exact candidate ranks + within-segment ranks -> sorted =====
__global__ __launch_bounds__(1024) void k_fin(const int* __restrict__ tinfo,
                                              const u32* __restrict__ basetot,
                                              const u64* __restrict__ gkeys,
                                              u64* __restrict__ sorted) {
    __shared__ u64 up[TOPK];
    __shared__ u64 cnd[4096];
    int img = blockIdx.x, tid = (int)threadIdx.x;
    int T = tinfo[3 * img];
    u32 r = (u32)tinfo[3 * img + 1];
    u32 m = (u32)tinfo[3 * img + 2];
    if (m > 4096u) m = 4096u;
    const u64* gk = gkeys + (size_t)img * GK;
    for (int i = tid; i < TOPK; i += 1024) up[i] = gk[i];
    for (u32 i = tid; i < m; i += 1024) cnd[i] = gk[TOPK + i];
    __syncthreads();
    u64* dst = sorted + (size_t)img * TOPK;
    // threshold-bin candidates -> slots [TOPK-r, TOPK)
    for (u32 i = tid; i < m; i += 1024) {
        u64 ki = cnd[i];
        u32 g = 0;
        for (u32 j = 0; j < m; ++j) g += (cnd[j] > ki) ? 1u : 0u;
        if (g < r) dst[TOPK - r + g] = ki;
    }
    // upper keys: exact rank within their (small) bin segment
    u32 upper = TOPK - r;
    const u32* bti = basetot + (size_t)img * NBT;
    for (u32 s = tid; s < upper; s += 1024) {
        u64 kk = up[s];
        if (kk == 0ull) { dst[s] = 0ull; continue; }
        int bb = binOf(kk);
        u32 v = bti[bb];
        u32 base = v >> 16, cc = v & 0xFFFFu;
        u32 g = 0;
        for (u32 j = 0; j < cc; ++j) g += (up[base + j] > kk) ? 1u : 0u;
        dst[base + g] = kk;
    }
}

// -------- Per-keypoint soft-argmax / dispersity / bilinear sample --------
__global__ __launch_bounds__(64) void k_out(const float* __restrict__ scores,
                                            const u64* __restrict__ sorted,
                                            float* __restrict__ out) {
    int gid = blockIdx.x * 64 + threadIdx.x;
    int b = gid / TOPK;
    int kp = gid & (TOPK - 1);
    const float* img = scores + (size_t)b * H * W;
    u64 key = sorted[(size_t)b * TOPK + kp];
    u32 idx = ~(u32)(key & 0xFFFFFFFFull);
    int ky = (int)(idx >> 10), kx = (int)(idx & 1023);
    ky = min(max(ky, 2), H - 3);
    kx = min(max(kx, 2), W - 3);
    float patch[25];
    float mx = -INFINITY;
#pragma unroll
    for (int dy = 0; dy < 5; ++dy)
#pragma unroll
        for (int dx = 0; dx < 5; ++dx) {
            float v = img[(ky + dy - 2) * W + (kx + dx - 2)];
            patch[dy * 5 + dx] = v;
            mx = fmaxf(mx, v);
        }
    float e[25];
    float ssum = 0.f, ex = 0.f, ey = 0.f;
#pragma unroll
    for (int p = 0; p < 25; ++p) {
        float t = expf((patch[p] - mx) / 0.1f);
        e[p] = t;
        ssum += t;
        ex += t * (float)((p % 5) - 2);
        ey += t * (float)((p / 5) - 2);
    }
    float xr = ex / ssum, yr = ey / ssum;
    float disp = 0.f;
#pragma unroll
    for (int p = 0; p < 25; ++p) {
        float ddx = ((float)((p % 5) - 2) - xr) * 0.5f;
        float ddy = ((float)((p / 5) - 2) - yr) * 0.5f;
        disp += e[p] * (ddx * ddx + ddy * ddy);
    }
    disp /= ssum;
    float kpx = ((float)kx + xr) / 1023.0f * 2.0f - 1.0f;
    float kpy = ((float)ky + yr) / 1023.0f * 2.0f - 1.0f;
    float px = (kpx + 1.0f) * 0.5f * 1023.0f;
    float py = (kpy + 1.0f) * 0.5f * 1023.0f;
    float fx = floorf(px), fy = floorf(py);
    float wx = px - fx, wy = py - fy;
    int x0 = (int)fminf(fmaxf(fx, 0.f), 1023.f);
    int x1 = (int)fminf(fmaxf(fx + 1.f, 0.f), 1023.f);
    int y0 = (int)fminf(fmaxf(fy, 0.f), 1023.f);
    int y1 = (int)fminf(fmaxf(fy + 1.f, 0.f), 1023.f);
    float v00 = img[y0 * W + x0], v01 = img[y0 * W + x1];
    float v10 = img[y1 * W + x0], v11 = img[y1 * W + x1];
    float sc = v00 * (1.f - wx) * (1.f - wy) + v01 * wx * (1.f - wy) +
               v10 * (1.f - wx) * wy + v11 * wx * wy;
    size_t kb = (size_t)b * TOPK + kp;
    out[kb * 2 + 0] = kpx;
    out[kb * 2 + 1] = kpy;
    out[(size_t)B * TOPK * 2 + kb] = disp;
    out[(size_t)B * TOPK * 3 + kb] = sc;
}

extern "C" void kernel_launch(void* const* d_in, const int* in_sizes, int n_in,
                              void* d_out, int out_size, void* d_ws, size_t ws_size,
                              hipStream_t stream) {
    const float* scores = (const float*)d_in[0];
    float* out = (float*)d_out;
    char* ws = (char*)d_ws;
    u64* surv = (u64*)ws;                                   // 8 MB
    u32* M = (u32*)(ws + 8388608);                          // 4 MB
    u32* offo = (u32*)(ws + 12582912);                      // 4 MB
    u32* basetot = (u32*)(ws + 16777216);                   // 512 KB
    u64* gkeys = (u64*)(ws + 17301504);                     // 1.25 MB
    u64* sorted = (u64*)(ws + 18612224);                    // 256 KB
    u32* cnt = (u32*)(ws + 18874368);                       // 32 B
    int* tinfo = (int*)(ws + 18874432);                     // 96 B

    hipMemsetAsync(cnt, 0, B * sizeof(u32), stream);

    k_nms<<<dim3(GDX, GDY, B), 256, 0, stream>>>(scores, surv, cnt);
    k_hist<<<B * NCH, 256, 0, stream>>>(surv, cnt, M);
    k_scan<<<B, 1024, 0, stream>>>(M, offo, basetot, tinfo, gkeys);
    k_scatter<<<B * NCH, 256, 0, stream>>>(surv, cnt, tinfo, offo, gkeys);
    k_fin<<<B, 1024, 0, stream>>>(tinfo, basetot, gkeys, sorted);
    k_out<<<(B * TOPK) / 64, 64, 0, stream>>>(scores, sorted, out);
}